// Round 3
// baseline (162.053 us; speedup 1.0000x reference)
//
#include <hip/hip_runtime.h>
#include <hip/hip_bf16.h>

#define B_ 1024
#define IN_ 512
#define OUT_ 512
#define BTILE 64
#define OTILE 16
#define ITILE 32
#define PSTRIDE 196   // words per i-row in p_lds: 16 o * 12 + 4 pad (oc*12 mod 32 -> max 2-way bank alias, free)
#define XSTRIDE 68    // BTILE + 4 pad (keeps 16B align)

__device__ __forceinline__ float fast_exp2(float x) {
#if __has_builtin(__builtin_amdgcn_exp2f)
    return __builtin_amdgcn_exp2f(x);
#else
    return __exp2f(x);
#endif
}
__device__ __forceinline__ float fast_fract(float x) {
#if __has_builtin(__builtin_amdgcn_fractf)
    return __builtin_amdgcn_fractf(x);
#else
    return x - floorf(x);
#endif
}
__device__ __forceinline__ float fast_cos_rev(float x) {  // cos(2*pi*x), x in revolutions
#if __has_builtin(__builtin_amdgcn_cosf)
    return __builtin_amdgcn_cosf(fast_fract(x));   // fract: exact range reduction (insurance per ISA note)
#else
    return __cosf(x * 6.2831853071795864f);
#endif
}
__device__ __forceinline__ float fast_rcp(float x) {
#if __has_builtin(__builtin_amdgcn_rcpf)
    return __builtin_amdgcn_rcpf(x);
#else
    return 1.0f / x;
#endif
}

__global__ __launch_bounds__(256) void chirplet_kernel(
    const float* __restrict__ x,
    const float* __restrict__ W,
    const float* __restrict__ Wc,
    const float* __restrict__ S,
    const float* __restrict__ T,
    const float* __restrict__ F,
    const float* __restrict__ bias,
    float* __restrict__ out)
{
    __shared__ float p_lds[ITILE * PSTRIDE];   // [i][o][12]: a,b,c2,d2,W,Wc (+pad)
    __shared__ float x_lds[ITILE * XSTRIDE];   // [i][b] transposed
    __shared__ float s_lds[ITILE * XSTRIDE];   // silu(x), same layout

    const int tid = threadIdx.x;
    const int o0 = blockIdx.x * OTILE;
    const int b0 = blockIdx.y * BTILE;

    // compute mapping: thread = (o within tile, 4 consecutive b)
    const int oc = tid & 15;        // 0..15
    const int bq = tid >> 4;        // 0..15 -> b = bq*4 + k

    // staging mappings
    const int xbl = tid >> 2;           // 0..63  b row
    const int xil = (tid & 3) * 8;      // i start (8 floats = two float4)
    const int pol = tid >> 4;           // 0..15  o row
    const int pil = (tid & 15) * 2;     // i start (2 floats = one float2)

    const float LOG2E = 1.4426950408889634f;
    const float GK    = 0.8493218002880191f;   // sqrt(0.5*log2(e)); exp(-0.5*u^2) = exp2(-(GK*u)^2)

    float acc[4] = {0.f, 0.f, 0.f, 0.f};

    for (int c = 0; c < IN_ / ITILE; ++c) {
        const int ib = c * ITILE;

        // ---- stage x tile (64 b x 32 i): fp32 load + silu, transposed to [i][b]
        {
            const float* xp = x + (size_t)(b0 + xbl) * IN_ + ib + xil;
            const float4 v0 = *(const float4*)xp;
            const float4 v1 = *(const float4*)(xp + 4);
            const float xf[8] = { v0.x, v0.y, v0.z, v0.w, v1.x, v1.y, v1.z, v1.w };
            #pragma unroll
            for (int j = 0; j < 8; ++j) {
                float sig = fast_rcp(1.0f + fast_exp2(-xf[j] * LOG2E));
                x_lds[(xil + j) * XSTRIDE + xbl] = xf[j];
                s_lds[(xil + j) * XSTRIDE + xbl] = xf[j] * sig;
            }
        }

        // ---- stage params (16 o x 32 i): fold into a,b,c2,d2,W,Wc
        {
            const size_t go = (size_t)(o0 + pol) * IN_ + ib + pil;
            const float2 sv = *(const float2*)(S + go);
            const float2 tv = *(const float2*)(T + go);
            const float2 fv = *(const float2*)(F + go);
            const float2 wv = *(const float2*)(W + go);
            const float2 cv = *(const float2*)(Wc + go);
            const float sa[2] = { sv.x, sv.y }, ta[2] = { tv.x, tv.y }, fa[2] = { fv.x, fv.y };
            const float wa[2] = { wv.x, wv.y }, ca[2] = { cv.x, cv.y };
            #pragma unroll
            for (int j = 0; j < 2; ++j) {
                float rs = fast_rcp(sa[j]);
                float a  = fa[j] * rs;            // cos multiplier (revolutions per x)
                float bb = -a * ta[j];            // cos offset
                float c2 = rs * GK;               // gaussian slope
                float d2 = -ta[j] * rs * GK;      // gaussian offset
                float* p = &p_lds[(pil + j) * PSTRIDE + pol * 12];
                p[0] = a; p[1] = bb; p[2] = c2; p[3] = d2; p[4] = wa[j]; p[5] = ca[j];
            }
        }
        __syncthreads();

        // ---- compute: each thread 4 b x 1 o over ITILE i's
        #pragma unroll 4
        for (int i = 0; i < ITILE; ++i) {
            const float4 abcd = *(const float4*)&p_lds[i * PSTRIDE + oc * 12];
            const float2 ww   = *(const float2*)&p_lds[i * PSTRIDE + oc * 12 + 4];
            const float4 xv   = *(const float4*)&x_lds[i * XSTRIDE + bq * 4];
            const float4 svv  = *(const float4*)&s_lds[i * XSTRIDE + bq * 4];
            const float xk[4] = { xv.x, xv.y, xv.z, xv.w };
            const float sk[4] = { svv.x, svv.y, svv.z, svv.w };
            #pragma unroll
            for (int k = 0; k < 4; ++k) {
                float rev = fmaf(abcd.x, xk[k], abcd.y);   // f*(x-t)/s  (revolutions)
                float co  = fast_cos_rev(rev);             // cos(2*pi*rev)
                float u   = fmaf(abcd.z, xk[k], abcd.w);   // GK*(x-t)/s
                float e   = fast_exp2(-(u * u));           // exp(-0.5*((x-t)/s)^2)
                acc[k] = fmaf(co * e, ww.y, acc[k]);       // chirplet * Wc
                acc[k] = fmaf(sk[k], ww.x, acc[k]);        // silu(x) * W
            }
        }
        __syncthreads();
    }

    // ---- epilogue: + bias, fp32 store
    const float bsf = bias[o0 + oc];
    #pragma unroll
    for (int k = 0; k < 4; ++k) {
        const int b = b0 + bq * 4 + k;
        out[(size_t)b * OUT_ + o0 + oc] = acc[k] + bsf;
    }
}

extern "C" void kernel_launch(void* const* d_in, const int* in_sizes, int n_in,
                              void* d_out, int out_size, void* d_ws, size_t ws_size,
                              hipStream_t stream) {
    const float* x    = (const float*)d_in[0];
    const float* W    = (const float*)d_in[1];
    const float* Wc   = (const float*)d_in[2];
    const float* S    = (const float*)d_in[3];
    const float* T    = (const float*)d_in[4];
    const float* F    = (const float*)d_in[5];
    const float* bias = (const float*)d_in[6];
    float* out = (float*)d_out;

    dim3 grid(OUT_ / OTILE, B_ / BTILE);   // 32 x 16 = 512 blocks
    chirplet_kernel<<<grid, 256, 0, stream>>>(x, W, Wc, S, T, F, bias, out);
}

// Round 4
// 152.665 us; speedup vs baseline: 1.0615x; 1.0615x over previous
//
#include <hip/hip_runtime.h>
#include <hip/hip_bf16.h>

#define B_ 1024
#define IN_ 512
#define OUT_ 512
#define BTILE 64
#define OTILE 16
#define ITILE 16
#define KSPLIT 4
#define KCHUNK (IN_ / KSPLIT)          // 128 i's per block
#define NCHUNKS (KCHUNK / ITILE)       // 8 staging chunks
#define PSTRIDE 196   // 16 o * 12 words + 4 pad; oc*12 stride -> max 2-way bank alias (free)
#define XSTRIDE 68    // BTILE + 4 pad, keeps 16B alignment for b128 reads

__device__ __forceinline__ float fast_exp2(float x) {
#if __has_builtin(__builtin_amdgcn_exp2f)
    return __builtin_amdgcn_exp2f(x);
#else
    return __exp2f(x);
#endif
}
__device__ __forceinline__ float fast_fract(float x) {
#if __has_builtin(__builtin_amdgcn_fractf)
    return __builtin_amdgcn_fractf(x);
#else
    return x - floorf(x);
#endif
}
__device__ __forceinline__ float fast_cos_rev(float x) {  // cos(2*pi*x), x in revolutions
#if __has_builtin(__builtin_amdgcn_cosf)
    return __builtin_amdgcn_cosf(fast_fract(x));   // fract = exact range reduction
#else
    return __cosf(x * 6.2831853071795864f);
#endif
}
__device__ __forceinline__ float fast_rcp(float x) {
#if __has_builtin(__builtin_amdgcn_rcpf)
    return __builtin_amdgcn_rcpf(x);
#else
    return 1.0f / x;
#endif
}

__global__ __launch_bounds__(256) void chirplet_kernel(
    const float* __restrict__ x,
    const float* __restrict__ W,
    const float* __restrict__ Wc,
    const float* __restrict__ S,
    const float* __restrict__ T,
    const float* __restrict__ F,
    const float* __restrict__ bias,
    float* __restrict__ out)
{
    __shared__ float p_lds[ITILE * PSTRIDE];   // [i][o][12]: a,b,c2,d2,W,Wc (+pad)
    __shared__ float x_lds[ITILE * XSTRIDE];   // [i][b] transposed
    __shared__ float s_lds[ITILE * XSTRIDE];   // silu(x), same layout

    const int tid = threadIdx.x;
    const int o0 = blockIdx.x * OTILE;
    const int b0 = blockIdx.y * BTILE;
    const int k0 = blockIdx.z * KCHUNK;

    // compute mapping: thread = (o within tile, 4 consecutive b)
    const int oc = tid & 15;        // 0..15
    const int bq = tid >> 4;        // 0..15 -> b = bq*4 + k

    // x staging: thread -> (row = tid>>2, col-quad = tid&3); write order rotated
    // per lane-quad so transposed LDS writes are <=2-way bank aliased (free).
    const int xrow = tid >> 2;          // 0..63
    const int xq   = tid & 3;           // col-quad 0..3 (4 floats each)

    // p staging: o-minor so LDS write stride is 12 words (2-way max, free)
    const int pol = tid & 15;           // o 0..15
    const int pi  = tid >> 4;           // i 0..15

    const float LOG2E = 1.4426950408889634f;
    const float GK    = 0.8493218002880191f;   // sqrt(0.5*log2(e)); exp(-0.5*u^2)=exp2(-(GK*u)^2)

    float acc[4] = {0.f, 0.f, 0.f, 0.f};

    for (int c = 0; c < NCHUNKS; ++c) {
        const int ib = k0 + c * ITILE;

        // ---- stage x tile (64 b x 16 i): coalesced load, silu, transpose to [i][b]
        {
            const float4 v = *(const float4*)(x + (size_t)(b0 + xrow) * IN_ + ib + xq * 4);
            const float xf[4] = { v.x, v.y, v.z, v.w };
            #pragma unroll
            for (int j = 0; j < 4; ++j) {
                const int jj  = (j + xq) & 3;           // rotation breaks 4-way bank alias
                const int col = xq * 4 + jj;
                float xv  = xf[jj];
                float sig = fast_rcp(1.0f + fast_exp2(-xv * LOG2E));
                x_lds[col * XSTRIDE + xrow] = xv;
                s_lds[col * XSTRIDE + xrow] = xv * sig;
            }
        }

        // ---- stage params (16 o x 16 i): one (o,i) per thread, fold coefficients
        {
            const size_t go = (size_t)(o0 + pol) * IN_ + ib + pi;
            const float s  = S[go];
            const float t  = T[go];
            const float f  = F[go];
            const float w  = W[go];
            const float wc = Wc[go];
            const float rs = fast_rcp(s);
            const float a  = f * rs;              // cos multiplier (revolutions per x)
            float4 p0; float2 p1;
            p0.x = a; p0.y = -a * t;              // cos offset
            p0.z = rs * GK; p0.w = -t * rs * GK;  // gaussian slope/offset
            p1.x = w; p1.y = wc;
            float* p = &p_lds[pi * PSTRIDE + pol * 12];
            *(float4*)p = p0;                     // 48B-aligned -> ds_write_b128
            *(float2*)(p + 4) = p1;               // ds_write_b64
        }
        __syncthreads();

        // ---- compute: each thread 4 b x 1 o over ITILE i's
        #pragma unroll 4
        for (int i = 0; i < ITILE; ++i) {
            const float4 abcd = *(const float4*)&p_lds[i * PSTRIDE + oc * 12];
            const float2 ww   = *(const float2*)&p_lds[i * PSTRIDE + oc * 12 + 4];
            const float4 xv   = *(const float4*)&x_lds[i * XSTRIDE + bq * 4];
            const float4 svv  = *(const float4*)&s_lds[i * XSTRIDE + bq * 4];
            const float xk[4] = { xv.x, xv.y, xv.z, xv.w };
            const float sk[4] = { svv.x, svv.y, svv.z, svv.w };
            #pragma unroll
            for (int k = 0; k < 4; ++k) {
                float rev = fmaf(abcd.x, xk[k], abcd.y);   // f*(x-t)/s  (revolutions)
                float co  = fast_cos_rev(rev);             // cos(2*pi*rev)
                float u   = fmaf(abcd.z, xk[k], abcd.w);   // GK*(x-t)/s
                float e   = fast_exp2(-(u * u));           // exp(-0.5*((x-t)/s)^2)
                acc[k] = fmaf(co * e, ww.y, acc[k]);       // chirplet * Wc
                acc[k] = fmaf(sk[k], ww.x, acc[k]);        // silu(x) * W
            }
        }
        __syncthreads();
    }

    // ---- epilogue: bias (once, from kslice 0) + fp32 atomic accumulate across kslices
    const float badd = (blockIdx.z == 0) ? bias[o0 + oc] : 0.0f;
    #pragma unroll
    for (int k = 0; k < 4; ++k) {
        const int b = b0 + bq * 4 + k;
        float* dst = &out[(size_t)b * OUT_ + o0 + oc];
#if defined(__HIP_DEVICE_COMPILE__)
        unsafeAtomicAdd(dst, acc[k] + badd);   // HW global_atomic_add_f32
#else
        atomicAdd(dst, acc[k] + badd);
#endif
    }
}

extern "C" void kernel_launch(void* const* d_in, const int* in_sizes, int n_in,
                              void* d_out, int out_size, void* d_ws, size_t ws_size,
                              hipStream_t stream) {
    const float* x    = (const float*)d_in[0];
    const float* W    = (const float*)d_in[1];
    const float* Wc   = (const float*)d_in[2];
    const float* S    = (const float*)d_in[3];
    const float* T    = (const float*)d_in[4];
    const float* F    = (const float*)d_in[5];
    const float* bias = (const float*)d_in[6];
    float* out = (float*)d_out;

    // d_out is poisoned before every launch; atomics need zeroed destination
    hipMemsetAsync(out, 0, (size_t)out_size * sizeof(float), stream);

    dim3 grid(OUT_ / OTILE, B_ / BTILE, KSPLIT);   // 32 x 16 x 4 = 2048 blocks
    chirplet_kernel<<<grid, 256, 0, stream>>>(x, W, Wc, S, T, F, bias, out);
}

// Round 5
// 139.058 us; speedup vs baseline: 1.1654x; 1.0978x over previous
//
#include <hip/hip_runtime.h>
#include <hip/hip_bf16.h>

#define B_ 1024
#define IN_ 512
#define OUT_ 512
#define BTILE 64
#define OTILE 16
#define ITILE 16
#define KSPLIT 8
#define KCHUNK (IN_ / KSPLIT)          // 64 i's per block
#define NCHUNKS (KCHUNK / ITILE)       // 4 staging chunks
#define PSTRIDE 196   // 16 o * 12 words + 4 pad; oc*12 read stride -> 2-way bank alias (free)
#define XSTRIDE 68    // BTILE + 4 pad; 68 % 32 == 4 -> staging writes exactly 2-way (free)

__device__ __forceinline__ float fast_exp2(float x) {
#if __has_builtin(__builtin_amdgcn_exp2f)
    return __builtin_amdgcn_exp2f(x);
#else
    return __exp2f(x);
#endif
}
__device__ __forceinline__ float fast_cos_rev(float x) {  // cos(2*pi*x), x in revolutions
#if __has_builtin(__builtin_amdgcn_cosf)
    return __builtin_amdgcn_cosf(x);   // v_cos_f32 valid domain +-256 revs; |x| <= ~8 here
#else
    return __cosf(x * 6.2831853071795864f);
#endif
}
__device__ __forceinline__ float fast_rcp(float x) {
#if __has_builtin(__builtin_amdgcn_rcpf)
    return __builtin_amdgcn_rcpf(x);
#else
    return 1.0f / x;
#endif
}

__global__ __launch_bounds__(256) void chirplet_kernel(
    const float* __restrict__ x,
    const float* __restrict__ W,
    const float* __restrict__ Wc,
    const float* __restrict__ S,
    const float* __restrict__ T,
    const float* __restrict__ F,
    const float* __restrict__ bias,
    float* __restrict__ out)
{
    __shared__ float p_lds[ITILE * PSTRIDE];   // [i][o][12]: a,b,c2,d2,W,Wc (+pad)
    __shared__ float x_lds[ITILE * XSTRIDE];   // [i][b] transposed
    __shared__ float s_lds[ITILE * XSTRIDE];   // silu(x), same layout

    const int tid = threadIdx.x;
    const int o0 = blockIdx.x * OTILE;
    const int b0 = blockIdx.y * BTILE;
    const int k0 = blockIdx.z * KCHUNK;

    // compute mapping: thread = (o within tile, 4 consecutive b)
    const int oc = tid & 15;        // 0..15
    const int bq = tid >> 4;        // 0..15 -> b = bq*4 + k

    // x staging: row = tid>>2 (b), col-quad = tid&3 (4 i's); bank = 16*xq + 4j + xrow
    // -> exactly 2 lanes per bank (free, m136). NO rotation (R4's rotation made 3-way).
    const int xrow = tid >> 2;          // 0..63
    const int xq   = tid & 3;           // 0..3

    // p staging: o-minor (stride 12 words); b128 wave-write lands at the 8-cycle minimum
    const int pol = tid & 15;           // o 0..15
    const int pi  = tid >> 4;           // i 0..15

    const float LOG2E = 1.4426950408889634f;
    const float GK    = 0.8493218002880191f;   // sqrt(0.5*log2(e)); exp(-0.5*u^2)=exp2(-(GK*u)^2)

    float acc[4] = {0.f, 0.f, 0.f, 0.f};

    for (int c = 0; c < NCHUNKS; ++c) {
        const int ib = k0 + c * ITILE;

        // ---- stage x tile (64 b x 16 i): coalesced load, silu, transpose to [i][b]
        {
            const float4 v = *(const float4*)(x + (size_t)(b0 + xrow) * IN_ + ib + xq * 4);
            const float xf[4] = { v.x, v.y, v.z, v.w };
            #pragma unroll
            for (int j = 0; j < 4; ++j) {
                const int col = xq * 4 + j;
                float xv  = xf[j];
                float sig = fast_rcp(1.0f + fast_exp2(-xv * LOG2E));
                x_lds[col * XSTRIDE + xrow] = xv;
                s_lds[col * XSTRIDE + xrow] = xv * sig;
            }
        }

        // ---- stage params (16 o x 16 i): one (o,i) per thread, fold coefficients
        {
            const size_t go = (size_t)(o0 + pol) * IN_ + ib + pi;
            const float s  = S[go];
            const float t  = T[go];
            const float f  = F[go];
            const float w  = W[go];
            const float wc = Wc[go];
            const float rs = fast_rcp(s);
            const float a  = f * rs;              // cos multiplier (revolutions per x)
            float4 p0; float2 p1;
            p0.x = a; p0.y = -a * t;              // cos offset
            p0.z = rs * GK; p0.w = -t * rs * GK;  // gaussian slope/offset
            p1.x = w; p1.y = wc;
            float* p = &p_lds[pi * PSTRIDE + pol * 12];
            *(float4*)p = p0;                     // ds_write_b128
            *(float2*)(p + 4) = p1;               // ds_write_b64
        }
        __syncthreads();

        // ---- compute: each thread 4 b x 1 o over ITILE i's
        #pragma unroll 4
        for (int i = 0; i < ITILE; ++i) {
            const float4 abcd = *(const float4*)&p_lds[i * PSTRIDE + oc * 12];
            const float2 ww   = *(const float2*)&p_lds[i * PSTRIDE + oc * 12 + 4];
            const float4 xv   = *(const float4*)&x_lds[i * XSTRIDE + bq * 4];
            const float4 svv  = *(const float4*)&s_lds[i * XSTRIDE + bq * 4];
            const float xk[4] = { xv.x, xv.y, xv.z, xv.w };
            const float sk[4] = { svv.x, svv.y, svv.z, svv.w };
            #pragma unroll
            for (int k = 0; k < 4; ++k) {
                float rev = fmaf(abcd.x, xk[k], abcd.y);   // f*(x-t)/s  (revolutions)
                float co  = fast_cos_rev(rev);             // cos(2*pi*rev)
                float u   = fmaf(abcd.z, xk[k], abcd.w);   // GK*(x-t)/s
                float e   = fast_exp2(-(u * u));           // exp(-0.5*((x-t)/s)^2)
                acc[k] = fmaf(co * e, ww.y, acc[k]);       // chirplet * Wc
                acc[k] = fmaf(sk[k], ww.x, acc[k]);        // silu(x) * W
            }
        }
        __syncthreads();
    }

    // ---- epilogue: bias (once, from kslice 0) + fp32 atomic accumulate across kslices
    const float badd = (blockIdx.z == 0) ? bias[o0 + oc] : 0.0f;
    #pragma unroll
    for (int k = 0; k < 4; ++k) {
        const int b = b0 + bq * 4 + k;
        float* dst = &out[(size_t)b * OUT_ + o0 + oc];
#if defined(__HIP_DEVICE_COMPILE__)
        unsafeAtomicAdd(dst, acc[k] + badd);   // HW global_atomic_add_f32
#else
        atomicAdd(dst, acc[k] + badd);
#endif
    }
}

extern "C" void kernel_launch(void* const* d_in, const int* in_sizes, int n_in,
                              void* d_out, int out_size, void* d_ws, size_t ws_size,
                              hipStream_t stream) {
    const float* x    = (const float*)d_in[0];
    const float* W    = (const float*)d_in[1];
    const float* Wc   = (const float*)d_in[2];
    const float* S    = (const float*)d_in[3];
    const float* T    = (const float*)d_in[4];
    const float* F    = (const float*)d_in[5];
    const float* bias = (const float*)d_in[6];
    float* out = (float*)d_out;

    // d_out is poisoned before every launch; atomics need zeroed destination
    hipMemsetAsync(out, 0, (size_t)out_size * sizeof(float), stream);

    dim3 grid(OUT_ / OTILE, B_ / BTILE, KSPLIT);   // 32 x 16 x 8 = 4096 blocks
    chirplet_kernel<<<grid, 256, 0, stream>>>(x, W, Wc, S, T, F, bias, out);
}

// Round 6
// 135.126 us; speedup vs baseline: 1.1993x; 1.0291x over previous
//
#include <hip/hip_runtime.h>
#include <hip/hip_bf16.h>

#define B_ 1024
#define IN_ 512
#define OUT_ 512
#define BTILE 64
#define OTILE 16
#define ITILE 16
#define KSPLIT 8
#define KCHUNK (IN_ / KSPLIT)          // 64 i's per block
#define NCHUNKS (KCHUNK / ITILE)       // 4 staging chunks
#define P4STRIDE 64   // 16 o * 4 words; reads at oc*4 -> 2-way bank alias (free)
#define P2STRIDE 32   // 16 o * 2 words; reads at oc*2 -> conflict-free
#define XSTRIDE 68    // BTILE + 4 pad; 68 % 32 == 4 -> staging writes exactly 2-way (free)

__device__ __forceinline__ float fast_exp2(float x) {
#if __has_builtin(__builtin_amdgcn_exp2f)
    return __builtin_amdgcn_exp2f(x);
#else
    return __exp2f(x);
#endif
}
__device__ __forceinline__ float fast_log2(float x) {
#if __has_builtin(__builtin_amdgcn_logf)
    return __builtin_amdgcn_logf(x);   // v_log_f32 = log2
#else
    return __log2f(x);
#endif
}
__device__ __forceinline__ float fast_cos_rev(float x) {  // cos(2*pi*x), x in revolutions
#if __has_builtin(__builtin_amdgcn_cosf)
    return __builtin_amdgcn_cosf(x);   // v_cos_f32 valid domain +-256 revs; |x| <= ~9 here
#else
    return __cosf(x * 6.2831853071795864f);
#endif
}
__device__ __forceinline__ float fast_rcp(float x) {
#if __has_builtin(__builtin_amdgcn_rcpf)
    return __builtin_amdgcn_rcpf(x);
#else
    return 1.0f / x;
#endif
}

__global__ __launch_bounds__(256, 8) void chirplet_kernel(
    const float* __restrict__ x,
    const float* __restrict__ W,
    const float* __restrict__ Wc,
    const float* __restrict__ S,
    const float* __restrict__ T,
    const float* __restrict__ F,
    const float* __restrict__ bias,
    float* __restrict__ out)
{
    // p split: float4 {a, b', c2, d2} + float2 {lw, w}.  14.8 KB total -> 8 blocks/CU.
    __shared__ __align__(16) float p4_lds[ITILE * P4STRIDE];
    __shared__ __align__(16) float p2_lds[ITILE * P2STRIDE];
    __shared__ __align__(16) float x_lds[ITILE * XSTRIDE];   // [i][b] transposed
    __shared__ __align__(16) float s_lds[ITILE * XSTRIDE];   // silu(x)

    const int tid = threadIdx.x;
    const int o0 = blockIdx.x * OTILE;
    const int b0 = blockIdx.y * BTILE;
    const int k0 = blockIdx.z * KCHUNK;

    // compute mapping: thread = (o within tile, 4 consecutive b)
    const int oc = tid & 15;        // 0..15
    const int bq = tid >> 4;        // 0..15 -> b = bq*4 + k

    // x staging: row = tid>>2 (b), col-quad = tid&3; writes exactly 2-way (free)
    const int xrow = tid >> 2;          // 0..63
    const int xq   = tid & 3;           // 0..3

    // p staging: one (o,i) per thread; writes spread evenly over all 32 banks
    const int pol = tid & 15;           // o 0..15
    const int pi  = tid >> 4;           // i 0..15

    const float LOG2E = 1.4426950408889634f;
    const float GK    = 0.8493218002880191f;   // sqrt(0.5*log2(e)); exp(-0.5*u^2)=exp2(-(GK*u)^2)

    float acc[4] = {0.f, 0.f, 0.f, 0.f};

    for (int c = 0; c < NCHUNKS; ++c) {
        const int ib = k0 + c * ITILE;

        // ---- stage x tile (64 b x 16 i): coalesced load, silu, transpose to [i][b]
        {
            const float4 v = *(const float4*)(x + (size_t)(b0 + xrow) * IN_ + ib + xq * 4);
            const float xf[4] = { v.x, v.y, v.z, v.w };
            #pragma unroll
            for (int j = 0; j < 4; ++j) {
                const int col = xq * 4 + j;
                float xv  = xf[j];
                float sig = fast_rcp(1.0f + fast_exp2(-xv * LOG2E));
                x_lds[col * XSTRIDE + xrow] = xv;
                s_lds[col * XSTRIDE + xrow] = xv * sig;
            }
        }

        // ---- stage params (16 o x 16 i): fold coefficients.
        // sign(Wc) folded into cos phase (+0.5 rev flips sign: cos is even, shift is exact);
        // |Wc| folded into exp2 argument as lw = log2|Wc| (Wc=0 -> -inf -> exp2 -> 0).
        {
            const size_t go = (size_t)(o0 + pol) * IN_ + k0 + c * ITILE + pi;
            const float s  = S[go];
            const float t  = T[go];
            const float f  = F[go];
            const float w  = W[go];
            const float wc = Wc[go];
            const float rs = fast_rcp(s);
            const float a  = f * rs;                       // revolutions per x
            float4 p0; float2 p1;
            p0.x = a;
            p0.y = -a * t + (wc < 0.0f ? 0.5f : 0.0f);     // phase offset + sign(Wc)
            p0.z = rs * GK;
            p0.w = -t * rs * GK;
            p1.x = fast_log2(fabsf(wc));                   // lw
            p1.y = w;
            *(float4*)&p4_lds[pi * P4STRIDE + pol * 4] = p0;   // ds_write_b128
            *(float2*)&p2_lds[pi * P2STRIDE + pol * 2] = p1;   // ds_write_b64
        }
        __syncthreads();

        // ---- compute: each thread 4 b x 1 o over ITILE i's
        // per element: 5 full-rate + 2 transcendental VALU ops
        #pragma unroll 4
        for (int i = 0; i < ITILE; ++i) {
            const float4 abcd = *(const float4*)&p4_lds[i * P4STRIDE + oc * 4];
            const float2 lww  = *(const float2*)&p2_lds[i * P2STRIDE + oc * 2];
            const float4 xv   = *(const float4*)&x_lds[i * XSTRIDE + bq * 4];
            const float4 svv  = *(const float4*)&s_lds[i * XSTRIDE + bq * 4];
            const float xk[4] = { xv.x, xv.y, xv.z, xv.w };
            const float sk[4] = { svv.x, svv.y, svv.z, svv.w };
            #pragma unroll
            for (int k = 0; k < 4; ++k) {
                float rev = fmaf(abcd.x, xk[k], abcd.y);   // f*(x-t)/s + sign phase
                float co  = fast_cos_rev(rev);             // +-cos(2*pi*.)
                float u   = fmaf(abcd.z, xk[k], abcd.w);   // GK*(x-t)/s
                float e   = fast_exp2(fmaf(-u, u, lww.x)); // |Wc|*exp(-0.5*((x-t)/s)^2)
                acc[k] = fmaf(co, e, acc[k]);              // chirplet * Wc (sign in co)
                acc[k] = fmaf(sk[k], lww.y, acc[k]);       // silu(x) * W
            }
        }
        __syncthreads();
    }

    // ---- epilogue: bias (once, from kslice 0) + fp32 atomic accumulate across kslices
    const float badd = (blockIdx.z == 0) ? bias[o0 + oc] : 0.0f;
    #pragma unroll
    for (int k = 0; k < 4; ++k) {
        const int b = b0 + bq * 4 + k;
        float* dst = &out[(size_t)b * OUT_ + o0 + oc];
#if defined(__HIP_DEVICE_COMPILE__)
        unsafeAtomicAdd(dst, acc[k] + badd);   // HW global_atomic_add_f32
#else
        atomicAdd(dst, acc[k] + badd);
#endif
    }
}

extern "C" void kernel_launch(void* const* d_in, const int* in_sizes, int n_in,
                              void* d_out, int out_size, void* d_ws, size_t ws_size,
                              hipStream_t stream) {
    const float* x    = (const float*)d_in[0];
    const float* W    = (const float*)d_in[1];
    const float* Wc   = (const float*)d_in[2];
    const float* S    = (const float*)d_in[3];
    const float* T    = (const float*)d_in[4];
    const float* F    = (const float*)d_in[5];
    const float* bias = (const float*)d_in[6];
    float* out = (float*)d_out;

    // d_out is poisoned before every launch; atomics need zeroed destination
    hipMemsetAsync(out, 0, (size_t)out_size * sizeof(float), stream);

    dim3 grid(OUT_ / OTILE, B_ / BTILE, KSPLIT);   // 32 x 16 x 8 = 4096 blocks
    chirplet_kernel<<<grid, 256, 0, stream>>>(x, W, Wc, S, T, F, bias, out);
}